// Round 2
// baseline (256.292 us; speedup 1.0000x reference)
//
#include <hip/hip_runtime.h>

// Problem constants
#define BATCH 8
#define NQ    2048
#define NKV   2048
#define DIN   512
#define DKEY  512
#define DMOD  512

typedef __attribute__((ext_vector_type(8))) short bf16x8;
typedef __attribute__((ext_vector_type(4))) float f32x4;

__device__ __forceinline__ unsigned short f2bf(float f) {
  unsigned int u = __builtin_bit_cast(unsigned int, f);
  u += 0x7fffu + ((u >> 16) & 1u);   // RNE
  return (unsigned short)(u >> 16);
}
__device__ __forceinline__ float bf2f(unsigned short h) {
  unsigned int u = ((unsigned int)h) << 16;
  return __builtin_bit_cast(float, u);
}

// ---------------------------------------------------------------------------
// Mask element-size detector: byte pos %4==1 nonzero <=> 1-byte bool elements.
// (int32/float32 0/1 values always have byte1 == 0.)
__global__ void detect_mode(const unsigned int* __restrict__ mask, int* __restrict__ flag) {
  __shared__ int c1s;
  if (threadIdx.x == 0) c1s = 0;
  __syncthreads();
  int c1 = 0;
  for (int i = threadIdx.x; i < 16384; i += 256) {
    unsigned int u = mask[i];
    if (u & 0x0000ff00u) c1++;
  }
  atomicAdd(&c1s, c1);
  __syncthreads();
  if (threadIdx.x == 0) *flag = (c1s > 0) ? 1 : 4;  // element size in bytes
}

// ---------------------------------------------------------------------------
// f32 -> bf16 convert (vectorized, grid-stride over float4s)
__global__ void cvt_bf16(const float* __restrict__ in, unsigned short* __restrict__ out, int n4) {
  int i = blockIdx.x * blockDim.x + threadIdx.x;
  const int stride = gridDim.x * blockDim.x;
  for (; i < n4; i += stride) {
    float4 v = ((const float4*)in)[i];
    ushort4 o;
    o.x = f2bf(v.x); o.y = f2bf(v.y); o.z = f2bf(v.z); o.w = f2bf(v.w);
    ((ushort4*)out)[i] = o;
  }
}

// f32 [512x512] -> bf16 transposed [512x512] (Wt[n][k] = W[k][n])
__global__ void cvt_w_transpose(const float* __restrict__ W, unsigned short* __restrict__ Wt) {
  int idx = blockIdx.x * 256 + threadIdx.x;  // 0..262143
  int k = idx >> 9, n = idx & 511;
  Wt[n * 512 + k] = f2bf(W[idx]);
}

// ---------------------------------------------------------------------------
// bf16 GEMM, C = A[M,K] * Bt[N,K]^T.  128x128 tile, BK=32, 4 waves,
// global_load_lds width 16, mfma_f32_16x16x32_bf16 (m97-style).
// out_mode: 0 = bf16 C[row*ldO+col]; 1 = bf16 transposed C[col*ldO+row];
//           2 = f32 C[row*ldO+col]
__global__ __launch_bounds__(256) void gemm_bt(
    const unsigned short* __restrict__ A,
    const unsigned short* __restrict__ Bt,
    void* __restrict__ Cout,
    int K, long ldB,
    long batchA, long batchB, long batchC,
    int out_mode, long ldO)
{
  __shared__ unsigned short Al[128][32];
  __shared__ unsigned short Bl[128][32];
  const unsigned short* Ab = A + (size_t)blockIdx.z * batchA;
  const unsigned short* Bb = Bt + (size_t)blockIdx.z * batchB;
  const long bm = (long)blockIdx.x * 128;
  const long bn = (long)blockIdx.y * 128;
  const int t = threadIdx.x;
  const int lane = t & 63;
  const int w = t >> 6;
  const int wm = (w >> 1) * 64, wn = (w & 1) * 64;
  const int fr = lane & 15, fq = lane >> 4;

  f32x4 acc[4][4] = {};

  const int slot0 = t, slot1 = 256 + t;
  const int r0 = slot0 >> 2, s0 = slot0 & 3;
  const int r1 = slot1 >> 2, s1 = slot1 & 3;

  const int nk = K >> 5;
  for (int kt = 0; kt < nk; ++kt) {
    const long k0 = (long)kt << 5;
    __builtin_amdgcn_global_load_lds(
        (const __attribute__((address_space(1))) unsigned int*)(Ab + (bm + r0) * K + k0 + s0 * 8),
        (__attribute__((address_space(3))) unsigned int*)(&Al[0][0] + slot0 * 8), 16, 0, 0);
    __builtin_amdgcn_global_load_lds(
        (const __attribute__((address_space(1))) unsigned int*)(Ab + (bm + r1) * K + k0 + s1 * 8),
        (__attribute__((address_space(3))) unsigned int*)(&Al[0][0] + slot1 * 8), 16, 0, 0);
    __builtin_amdgcn_global_load_lds(
        (const __attribute__((address_space(1))) unsigned int*)(Bb + (bn + r0) * ldB + k0 + s0 * 8),
        (__attribute__((address_space(3))) unsigned int*)(&Bl[0][0] + slot0 * 8), 16, 0, 0);
    __builtin_amdgcn_global_load_lds(
        (const __attribute__((address_space(1))) unsigned int*)(Bb + (bn + r1) * ldB + k0 + s1 * 8),
        (__attribute__((address_space(3))) unsigned int*)(&Bl[0][0] + slot1 * 8), 16, 0, 0);
    __syncthreads();  // compiler drains vmcnt before s_barrier -> LDS ready

    bf16x8 af[4], bfr[4];
#pragma unroll
    for (int mi = 0; mi < 4; ++mi)
      af[mi] = *(const bf16x8*)&Al[wm + mi * 16 + fr][fq * 8];
#pragma unroll
    for (int ni = 0; ni < 4; ++ni)
      bfr[ni] = *(const bf16x8*)&Bl[wn + ni * 16 + fr][fq * 8];
#pragma unroll
    for (int mi = 0; mi < 4; ++mi)
#pragma unroll
      for (int ni = 0; ni < 4; ++ni)
        acc[mi][ni] = __builtin_amdgcn_mfma_f32_16x16x32_bf16(af[mi], bfr[ni], acc[mi][ni], 0, 0, 0);
    __syncthreads();
  }

  // Epilogue. C/D frag layout: col = lane&15, row = (lane>>4)*4 + r  [m89-verified]
  const long zb = blockIdx.z;
  if (out_mode == 2) {
    float* C = (float*)Cout + zb * batchC;
#pragma unroll
    for (int mi = 0; mi < 4; ++mi)
#pragma unroll
      for (int ni = 0; ni < 4; ++ni) {
        const long row = bm + wm + mi * 16 + fq * 4;
        const long col = bn + wn + ni * 16 + fr;
#pragma unroll
        for (int r = 0; r < 4; ++r)
          C[(row + r) * ldO + col] = acc[mi][ni][r];
      }
  } else if (out_mode == 0) {
    unsigned short* C = (unsigned short*)Cout + zb * batchC;
#pragma unroll
    for (int mi = 0; mi < 4; ++mi)
#pragma unroll
      for (int ni = 0; ni < 4; ++ni) {
        const long row = bm + wm + mi * 16 + fq * 4;
        const long col = bn + wn + ni * 16 + fr;
#pragma unroll
        for (int r = 0; r < 4; ++r)
          C[(row + r) * ldO + col] = f2bf(acc[mi][ni][r]);
      }
  } else {
    unsigned short* C = (unsigned short*)Cout + zb * batchC;
#pragma unroll
    for (int mi = 0; mi < 4; ++mi)
#pragma unroll
      for (int ni = 0; ni < 4; ++ni) {
        const long row = bm + wm + mi * 16 + fq * 4;
        const long col = bn + wn + ni * 16 + fr;
#pragma unroll
        for (int r = 0; r < 4; ++r)
          C[col * ldO + (row + r)] = f2bf(acc[mi][ni][r]);
      }
  }
}

// ---------------------------------------------------------------------------
// Masked softmax over rows of S (bf16, in place). One block per row (2048 keys).
// Mask applies at flat index row*2048 + n (the reference's reshape is flat-elementwise).
// Scale is applied AFTER masking (masked -> FLT_MIN*scale, still ~-1.5e37).
__global__ __launch_bounds__(256) void softmax_rows(
    unsigned short* __restrict__ S,
    const unsigned char* __restrict__ mask,
    const int* __restrict__ flag)
{
  const int t = threadIdx.x;
  const size_t base = (size_t)blockIdx.x * 2048 + (size_t)t * 8;
  uint4 sv = *(const uint4*)(S + base);

  float x[8];
  {
    unsigned int w0 = sv.x, w1 = sv.y, w2 = sv.z, w3 = sv.w;
    x[0] = bf2f((unsigned short)(w0 & 0xffff)); x[1] = bf2f((unsigned short)(w0 >> 16));
    x[2] = bf2f((unsigned short)(w1 & 0xffff)); x[3] = bf2f((unsigned short)(w1 >> 16));
    x[4] = bf2f((unsigned short)(w2 & 0xffff)); x[5] = bf2f((unsigned short)(w2 >> 16));
    x[6] = bf2f((unsigned short)(w3 & 0xffff)); x[7] = bf2f((unsigned short)(w3 >> 16));
  }

  const int esz = *flag;
  unsigned int mbits = 0;
  if (esz == 1) {
    unsigned long long mv = *(const unsigned long long*)(mask + base);
#pragma unroll
    for (int j = 0; j < 8; ++j)
      if ((mv >> (8 * j)) & 0xffULL) mbits |= 1u << j;
  } else {
    const uint4* mp = (const uint4*)(mask + base * 4);
    uint4 a = mp[0], b = mp[1];
    if (a.x) mbits |= 1u;   if (a.y) mbits |= 2u;
    if (a.z) mbits |= 4u;   if (a.w) mbits |= 8u;
    if (b.x) mbits |= 16u;  if (b.y) mbits |= 32u;
    if (b.z) mbits |= 64u;  if (b.w) mbits |= 128u;
  }

  const float SCALE = 0.04419417382415922f;  // 1/sqrt(512)
  float xs[8];
#pragma unroll
  for (int j = 0; j < 8; ++j) {
    float v = ((mbits >> j) & 1u) ? -3.4028234663852886e38f : x[j];
    xs[j] = v * SCALE;
  }

  float m = xs[0];
#pragma unroll
  for (int j = 1; j < 8; ++j) m = fmaxf(m, xs[j]);
#pragma unroll
  for (int off = 32; off > 0; off >>= 1) m = fmaxf(m, __shfl_xor(m, off));

  __shared__ float rm[4], rs[4];
  if ((t & 63) == 0) rm[t >> 6] = m;
  __syncthreads();
  m = fmaxf(fmaxf(rm[0], rm[1]), fmaxf(rm[2], rm[3]));

  float e[8], ssum = 0.f;
#pragma unroll
  for (int j = 0; j < 8; ++j) { e[j] = __expf(xs[j] - m); ssum += e[j]; }
#pragma unroll
  for (int off = 32; off > 0; off >>= 1) ssum += __shfl_xor(ssum, off);
  if ((t & 63) == 0) rs[t >> 6] = ssum;
  __syncthreads();
  ssum = rs[0] + rs[1] + rs[2] + rs[3];
  const float inv = 1.0f / ssum;

  unsigned int o0 = (unsigned int)f2bf(e[0] * inv) | ((unsigned int)f2bf(e[1] * inv) << 16);
  unsigned int o1 = (unsigned int)f2bf(e[2] * inv) | ((unsigned int)f2bf(e[3] * inv) << 16);
  unsigned int o2 = (unsigned int)f2bf(e[4] * inv) | ((unsigned int)f2bf(e[5] * inv) << 16);
  unsigned int o3 = (unsigned int)f2bf(e[6] * inv) | ((unsigned int)f2bf(e[7] * inv) << 16);
  uint4 ov; ov.x = o0; ov.y = o1; ov.z = o2; ov.w = o3;
  *(uint4*)(S + base) = ov;
}

// ---------------------------------------------------------------------------
extern "C" void kernel_launch(void* const* d_in, const int* in_sizes, int n_in,
                              void* d_out, int out_size, void* d_ws, size_t ws_size,
                              hipStream_t stream) {
  const float* node  = (const float*)d_in[0];
  const float* query = (const float*)d_in[1];
  const unsigned char* mask = (const unsigned char*)d_in[2];
  const float* wq = (const float*)d_in[3];
  const float* wk = (const float*)d_in[4];
  const float* wv = (const float*)d_in[5];
  float* out = (float*)d_out;

  char* ws = (char*)d_ws;
  // ws layout (bytes):
  //   [0, 16M)      Q   bf16 [16384][512]
  //   [16M, 32M)    K   bf16 [16384][512]
  //   [32M, 48M)    Vt  bf16 [512][16384]
  //   [48M, 112M)   S   bf16 [8][2048][2048]      (written after proj)
  //     overlapped: Xq bf16, Xn bf16, Wt's       (dead after proj)
  //   [112M]        mask-mode flag (int)
  unsigned short* Q   = (unsigned short*)(ws);
  unsigned short* Kb  = (unsigned short*)(ws + 16777216);
  unsigned short* Vt  = (unsigned short*)(ws + 33554432);
  unsigned short* S   = (unsigned short*)(ws + 50331648);
  unsigned short* Xq  = (unsigned short*)(ws + 50331648);
  unsigned short* Xn  = (unsigned short*)(ws + 50331648 + 16777216);
  unsigned short* Wqt = (unsigned short*)(ws + 50331648 + 33554432);
  unsigned short* Wkt = Wqt + 262144;
  unsigned short* Wvt = Wkt + 262144;
  int* flag = (int*)(ws + 117440512);

  detect_mode<<<1, 256, 0, stream>>>((const unsigned int*)mask, flag);

  cvt_bf16<<<2048, 256, 0, stream>>>(query, Xq, 2097152);
  cvt_bf16<<<2048, 256, 0, stream>>>(node,  Xn, 2097152);
  cvt_w_transpose<<<1024, 256, 0, stream>>>(wq, Wqt);
  cvt_w_transpose<<<1024, 256, 0, stream>>>(wk, Wkt);
  cvt_w_transpose<<<1024, 256, 0, stream>>>(wv, Wvt);

  // Projections: M=16384, N=512, K=512
  dim3 gp(128, 4, 1);
  gemm_bt<<<gp, 256, 0, stream>>>(Xq, Wqt, Q,  512, 512, 0, 0, 0, 0, 512);
  gemm_bt<<<gp, 256, 0, stream>>>(Xn, Wkt, Kb, 512, 512, 0, 0, 0, 0, 512);
  gemm_bt<<<gp, 256, 0, stream>>>(Xn, Wvt, Vt, 512, 512, 0, 0, 0, 1, 16384);  // V^T

  // Scores: per batch [2048x512] * [2048x512]^T -> S bf16 [2048x2048]
  dim3 gs(16, 16, 8);
  gemm_bt<<<gs, 256, 0, stream>>>(Q, Kb, S, 512, 512,
                                  1048576L, 1048576L, 4194304L, 0, 2048);

  // Masked scaled softmax over each row of S (in place)
  softmax_rows<<<16384, 256, 0, stream>>>(S, mask, flag);

  // PV: per batch [2048x2048] * Vt[512x16384 (+b*2048)]^T -> out f32 [2048x512]
  dim3 gv(16, 4, 8);
  gemm_bt<<<gv, 256, 0, stream>>>(S, Vt, out, 2048, 16384,
                                  4194304L, 2048L, 1048576L, 2, 512);
}

// Round 3
// 231.587 us; speedup vs baseline: 1.1067x; 1.1067x over previous
//
#include <hip/hip_runtime.h>

// Problem constants
#define BATCH 8
#define NQ    2048
#define NKV   2048
#define DIN   512
#define DKEY  512
#define DMOD  512

typedef __attribute__((ext_vector_type(8))) short bf16x8;
typedef __attribute__((ext_vector_type(4))) float f32x4;

__device__ __forceinline__ unsigned short f2bf(float f) {
  unsigned int u = __builtin_bit_cast(unsigned int, f);
  u += 0x7fffu + ((u >> 16) & 1u);   // RNE
  return (unsigned short)(u >> 16);
}
__device__ __forceinline__ float bf2f(unsigned short h) {
  unsigned int u = ((unsigned int)h) << 16;
  return __builtin_bit_cast(float, u);
}

// ---------------------------------------------------------------------------
// Mask element-size detector: byte pos %4==1 nonzero <=> 1-byte bool elements.
__global__ void detect_mode(const unsigned int* __restrict__ mask, int* __restrict__ flag) {
  __shared__ int c1s;
  if (threadIdx.x == 0) c1s = 0;
  __syncthreads();
  int c1 = 0;
  for (int i = threadIdx.x; i < 16384; i += 256) {
    unsigned int u = mask[i];
    if (u & 0x0000ff00u) c1++;
  }
  atomicAdd(&c1s, c1);
  __syncthreads();
  if (threadIdx.x == 0) *flag = (c1s > 0) ? 1 : 4;  // element size in bytes
}

// ---------------------------------------------------------------------------
// Both activation converts in one launch: grid = 16384 blocks x 256.
// i < 2097152 -> query float4s, else node float4s.
__global__ void cvt_two(const float* __restrict__ a, const float* __restrict__ b,
                        unsigned short* __restrict__ oa, unsigned short* __restrict__ ob) {
  int i = blockIdx.x * 256 + threadIdx.x;
  const float* src;
  unsigned short* dst;
  int j;
  if (i < 2097152) { src = a; dst = oa; j = i; }
  else             { src = b; dst = ob; j = i - 2097152; }
  float4 v = ((const float4*)src)[j];
  ushort4 o;
  o.x = f2bf(v.x); o.y = f2bf(v.y); o.z = f2bf(v.z); o.w = f2bf(v.w);
  ((ushort4*)dst)[j] = o;
}

// All 3 weight transposes in one launch (coalesced writes, cached strided reads).
// idx -> w (which weight), n (out row), k (out col): Wt[n*512+k] = W[k*512+n]
__global__ void cvt_w3(const float* __restrict__ wq, const float* __restrict__ wk,
                       const float* __restrict__ wv,
                       unsigned short* __restrict__ oq, unsigned short* __restrict__ ok,
                       unsigned short* __restrict__ ov) {
  int idx = blockIdx.x * 256 + threadIdx.x;  // 0..786431
  int w = idx >> 18;
  int rem = idx & 262143;
  int n = rem >> 9, k = rem & 511;
  const float* W = (w == 0) ? wq : (w == 1) ? wk : wv;
  unsigned short* O = (w == 0) ? oq : (w == 1) ? ok : ov;
  O[n * 512 + k] = f2bf(W[k * 512 + n]);
}

// ---------------------------------------------------------------------------
// Shared GEMM core: C = A[M,K] * Bt[N,K]^T on a 128x128 tile at (bm,bn).
// BK=32, 4 waves, global_load_lds width 16, mfma_f32_16x16x32_bf16.
// out_mode: 0 = bf16 C[row*ldO+col]; 2 = f32 C[row*ldO+col]
__device__ __forceinline__ void gemm_core(
    const unsigned short* Ab, const unsigned short* Bb, void* Cb,
    int K, long ldB, int out_mode, long ldO, long bm, long bn,
    unsigned short (*Al)[32], unsigned short (*Bl)[32])
{
  const int t = threadIdx.x;
  const int lane = t & 63;
  const int w = t >> 6;
  const int wm = (w >> 1) * 64, wn = (w & 1) * 64;
  const int fr = lane & 15, fq = lane >> 4;

  f32x4 acc[4][4] = {};

  const int slot0 = t, slot1 = 256 + t;
  const int r0 = slot0 >> 2, s0 = slot0 & 3;
  const int r1 = slot1 >> 2, s1 = slot1 & 3;

  const int nk = K >> 5;
  for (int kt = 0; kt < nk; ++kt) {
    const long k0 = (long)kt << 5;
    __builtin_amdgcn_global_load_lds(
        (const __attribute__((address_space(1))) unsigned int*)(Ab + (bm + r0) * K + k0 + s0 * 8),
        (__attribute__((address_space(3))) unsigned int*)(&Al[0][0] + slot0 * 8), 16, 0, 0);
    __builtin_amdgcn_global_load_lds(
        (const __attribute__((address_space(1))) unsigned int*)(Ab + (bm + r1) * K + k0 + s1 * 8),
        (__attribute__((address_space(3))) unsigned int*)(&Al[0][0] + slot1 * 8), 16, 0, 0);
    __builtin_amdgcn_global_load_lds(
        (const __attribute__((address_space(1))) unsigned int*)(Bb + (bn + r0) * ldB + k0 + s0 * 8),
        (__attribute__((address_space(3))) unsigned int*)(&Bl[0][0] + slot0 * 8), 16, 0, 0);
    __builtin_amdgcn_global_load_lds(
        (const __attribute__((address_space(1))) unsigned int*)(Bb + (bn + r1) * ldB + k0 + s1 * 8),
        (__attribute__((address_space(3))) unsigned int*)(&Bl[0][0] + slot1 * 8), 16, 0, 0);
    __syncthreads();  // compiler drains vmcnt before s_barrier -> LDS ready

    bf16x8 af[4], bfr[4];
#pragma unroll
    for (int mi = 0; mi < 4; ++mi)
      af[mi] = *(const bf16x8*)&Al[wm + mi * 16 + fr][fq * 8];
#pragma unroll
    for (int ni = 0; ni < 4; ++ni)
      bfr[ni] = *(const bf16x8*)&Bl[wn + ni * 16 + fr][fq * 8];
#pragma unroll
    for (int mi = 0; mi < 4; ++mi)
#pragma unroll
      for (int ni = 0; ni < 4; ++ni)
        acc[mi][ni] = __builtin_amdgcn_mfma_f32_16x16x32_bf16(af[mi], bfr[ni], acc[mi][ni], 0, 0, 0);
    __syncthreads();
  }

  // Epilogue. C/D frag layout: col = lane&15, row = (lane>>4)*4 + r  [m89-verified]
  if (out_mode == 2) {
    float* C = (float*)Cb;
#pragma unroll
    for (int mi = 0; mi < 4; ++mi)
#pragma unroll
      for (int ni = 0; ni < 4; ++ni) {
        const long row = bm + wm + mi * 16 + fq * 4;
        const long col = bn + wn + ni * 16 + fr;
#pragma unroll
        for (int r = 0; r < 4; ++r)
          C[(row + r) * ldO + col] = acc[mi][ni][r];
      }
  } else {
    unsigned short* C = (unsigned short*)Cb;
#pragma unroll
    for (int mi = 0; mi < 4; ++mi)
#pragma unroll
      for (int ni = 0; ni < 4; ++ni) {
        const long row = bm + wm + mi * 16 + fq * 4;
        const long col = bn + wn + ni * 16 + fr;
#pragma unroll
        for (int r = 0; r < 4; ++r)
          C[(row + r) * ldO + col] = f2bf(acc[mi][ni][r]);
      }
  }
}

// Generic batched GEMM kernel (scores, PV)
__global__ __launch_bounds__(256) void gemm_bt(
    const unsigned short* __restrict__ A,
    const unsigned short* __restrict__ Bt,
    void* __restrict__ Cout,
    int K, long ldB,
    long batchA, long batchB, long batchC,
    int out_mode, long ldO, int out_f32)
{
  __shared__ unsigned short Al[128][32];
  __shared__ unsigned short Bl[128][32];
  const unsigned short* Ab = A + (size_t)blockIdx.z * batchA;
  const unsigned short* Bb = Bt + (size_t)blockIdx.z * batchB;
  char* Cb = (char*)Cout + (size_t)blockIdx.z * batchC * (out_f32 ? 4 : 2);
  gemm_core(Ab, Bb, Cb, K, ldB, out_mode, ldO,
            (long)blockIdx.x * 128, (long)blockIdx.y * 128, Al, Bl);
}

// All three projections in one launch. grid(128, 4, 3).
//  z=0: Q  = Xq * Wqt^T   [16384x512]          (bm=bx, bn=by)
//  z=1: K  = Xn * Wkt^T   [16384x512]          (bm=bx, bn=by)
//  z=2: Vt = Wvt * Xn^T   [512x16384]          (bm=by, bn=bx)  -- coalesced Vt store
__global__ __launch_bounds__(256) void gemm_proj3(
    const unsigned short* __restrict__ Xq, const unsigned short* __restrict__ Xn,
    const unsigned short* __restrict__ Wqt, const unsigned short* __restrict__ Wkt,
    const unsigned short* __restrict__ Wvt,
    unsigned short* __restrict__ Q, unsigned short* __restrict__ Kb,
    unsigned short* __restrict__ Vt)
{
  __shared__ unsigned short Al[128][32];
  __shared__ unsigned short Bl[128][32];
  const int z = blockIdx.z;
  if (z == 0) {
    gemm_core(Xq, Wqt, Q, 512, 512, 0, 512,
              (long)blockIdx.x * 128, (long)blockIdx.y * 128, Al, Bl);
  } else if (z == 1) {
    gemm_core(Xn, Wkt, Kb, 512, 512, 0, 512,
              (long)blockIdx.x * 128, (long)blockIdx.y * 128, Al, Bl);
  } else {
    gemm_core(Wvt, Xn, Vt, 512, 512, 0, 16384,
              (long)blockIdx.y * 128, (long)blockIdx.x * 128, Al, Bl);
  }
}

// ---------------------------------------------------------------------------
// Masked softmax over rows of S (bf16, in place). One block per row (2048 keys).
// Mask applies at flat index row*2048 + n (the reference's reshape is flat-elementwise).
__global__ __launch_bounds__(256) void softmax_rows(
    unsigned short* __restrict__ S,
    const unsigned char* __restrict__ mask,
    const int* __restrict__ flag)
{
  const int t = threadIdx.x;
  const size_t base = (size_t)blockIdx.x * 2048 + (size_t)t * 8;
  uint4 sv = *(const uint4*)(S + base);

  float x[8];
  {
    unsigned int w0 = sv.x, w1 = sv.y, w2 = sv.z, w3 = sv.w;
    x[0] = bf2f((unsigned short)(w0 & 0xffff)); x[1] = bf2f((unsigned short)(w0 >> 16));
    x[2] = bf2f((unsigned short)(w1 & 0xffff)); x[3] = bf2f((unsigned short)(w1 >> 16));
    x[4] = bf2f((unsigned short)(w2 & 0xffff)); x[5] = bf2f((unsigned short)(w2 >> 16));
    x[6] = bf2f((unsigned short)(w3 & 0xffff)); x[7] = bf2f((unsigned short)(w3 >> 16));
  }

  const int esz = *flag;
  unsigned int mbits = 0;
  if (esz == 1) {
    unsigned long long mv = *(const unsigned long long*)(mask + base);
#pragma unroll
    for (int j = 0; j < 8; ++j)
      if ((mv >> (8 * j)) & 0xffULL) mbits |= 1u << j;
  } else {
    const uint4* mp = (const uint4*)(mask + base * 4);
    uint4 a = mp[0], b = mp[1];
    if (a.x) mbits |= 1u;   if (a.y) mbits |= 2u;
    if (a.z) mbits |= 4u;   if (a.w) mbits |= 8u;
    if (b.x) mbits |= 16u;  if (b.y) mbits |= 32u;
    if (b.z) mbits |= 64u;  if (b.w) mbits |= 128u;
  }

  const float SCALE = 0.04419417382415922f;  // 1/sqrt(512)
  float xs[8];
#pragma unroll
  for (int j = 0; j < 8; ++j) {
    float v = ((mbits >> j) & 1u) ? -3.4028234663852886e38f : x[j];
    xs[j] = v * SCALE;
  }

  float m = xs[0];
#pragma unroll
  for (int j = 1; j < 8; ++j) m = fmaxf(m, xs[j]);
#pragma unroll
  for (int off = 32; off > 0; off >>= 1) m = fmaxf(m, __shfl_xor(m, off));

  __shared__ float rm[4], rs[4];
  if ((t & 63) == 0) rm[t >> 6] = m;
  __syncthreads();
  m = fmaxf(fmaxf(rm[0], rm[1]), fmaxf(rm[2], rm[3]));

  float e[8], ssum = 0.f;
#pragma unroll
  for (int j = 0; j < 8; ++j) { e[j] = __expf(xs[j] - m); ssum += e[j]; }
#pragma unroll
  for (int off = 32; off > 0; off >>= 1) ssum += __shfl_xor(ssum, off);
  if ((t & 63) == 0) rs[t >> 6] = ssum;
  __syncthreads();
  ssum = rs[0] + rs[1] + rs[2] + rs[3];
  const float inv = 1.0f / ssum;

  unsigned int o0 = (unsigned int)f2bf(e[0] * inv) | ((unsigned int)f2bf(e[1] * inv) << 16);
  unsigned int o1 = (unsigned int)f2bf(e[2] * inv) | ((unsigned int)f2bf(e[3] * inv) << 16);
  unsigned int o2 = (unsigned int)f2bf(e[4] * inv) | ((unsigned int)f2bf(e[5] * inv) << 16);
  unsigned int o3 = (unsigned int)f2bf(e[6] * inv) | ((unsigned int)f2bf(e[7] * inv) << 16);
  uint4 ov; ov.x = o0; ov.y = o1; ov.z = o2; ov.w = o3;
  *(uint4*)(S + base) = ov;
}

// ---------------------------------------------------------------------------
extern "C" void kernel_launch(void* const* d_in, const int* in_sizes, int n_in,
                              void* d_out, int out_size, void* d_ws, size_t ws_size,
                              hipStream_t stream) {
  const float* node  = (const float*)d_in[0];
  const float* query = (const float*)d_in[1];
  const unsigned char* mask = (const unsigned char*)d_in[2];
  const float* wq = (const float*)d_in[3];
  const float* wk = (const float*)d_in[4];
  const float* wv = (const float*)d_in[5];
  float* out = (float*)d_out;

  char* ws = (char*)d_ws;
  // ws layout (bytes):
  //   [0, 16M)      Q   bf16 [16384][512]
  //   [16M, 32M)    K   bf16 [16384][512]
  //   [32M, 48M)    Vt  bf16 [512][16384]
  //   [48M, 112M)   S   bf16 [8][2048][2048]      (written after proj)
  //     overlapped: Xq bf16, Xn bf16, Wt's       (dead after proj)
  //   [112M]        mask-mode flag (int)
  unsigned short* Q   = (unsigned short*)(ws);
  unsigned short* Kb  = (unsigned short*)(ws + 16777216);
  unsigned short* Vt  = (unsigned short*)(ws + 33554432);
  unsigned short* S   = (unsigned short*)(ws + 50331648);
  unsigned short* Xq  = (unsigned short*)(ws + 50331648);
  unsigned short* Xn  = (unsigned short*)(ws + 50331648 + 16777216);
  unsigned short* Wqt = (unsigned short*)(ws + 50331648 + 33554432);
  unsigned short* Wkt = Wqt + 262144;
  unsigned short* Wvt = Wkt + 262144;
  int* flag = (int*)(ws + 117440512);

  detect_mode<<<1, 256, 0, stream>>>((const unsigned int*)mask, flag);

  cvt_two<<<16384, 256, 0, stream>>>(query, node, Xq, Xn);
  cvt_w3<<<3072, 256, 0, stream>>>(wq, wk, wv, Wqt, Wkt, Wvt);

  // Projections (one launch): Q, K, Vt
  dim3 gp(128, 4, 3);
  gemm_proj3<<<gp, 256, 0, stream>>>(Xq, Xn, Wqt, Wkt, Wvt, Q, Kb, Vt);

  // Scores: per batch [2048x512] * [2048x512]^T -> S bf16 [2048x2048]
  dim3 gs(16, 16, 8);
  gemm_bt<<<gs, 256, 0, stream>>>(Q, Kb, S, 512, 512,
                                  1048576L, 1048576L, 4194304L, 0, 2048, 0);

  // Masked scaled softmax over each row of S (in place)
  softmax_rows<<<16384, 256, 0, stream>>>(S, mask, flag);

  // PV: per batch [2048x2048] * Vt[512x16384 (+b*2048)]^T -> out f32 [2048x512]
  dim3 gv(16, 4, 8);
  gemm_bt<<<gv, 256, 0, stream>>>(S, Vt, out, 2048, 16384,
                                  4194304L, 2048L, 1048576L, 2, 512, 1);
}

// Round 4
// 220.899 us; speedup vs baseline: 1.1602x; 1.0484x over previous
//
#include <hip/hip_runtime.h>

// Problem constants
#define BATCH 8
#define NQ    2048
#define NKV   2048
#define DIN   512
#define DKEY  512
#define DMOD  512

typedef __attribute__((ext_vector_type(8))) short bf16x8;
typedef __attribute__((ext_vector_type(4))) float f32x4;

__device__ __forceinline__ unsigned short f2bf(float f) {
  unsigned int u = __builtin_bit_cast(unsigned int, f);
  u += 0x7fffu + ((u >> 16) & 1u);   // RNE
  return (unsigned short)(u >> 16);
}
__device__ __forceinline__ float bf2f(unsigned short h) {
  unsigned int u = ((unsigned int)h) << 16;
  return __builtin_bit_cast(float, u);
}

#define GLD16(gp, lp) __builtin_amdgcn_global_load_lds( \
    (const __attribute__((address_space(1))) unsigned int*)(gp), \
    (__attribute__((address_space(3))) unsigned int*)(lp), 16, 0, 0)

// ---------------------------------------------------------------------------
// Mask element-size detector: byte pos %4==1 nonzero <=> 1-byte bool elements.
__global__ void detect_mode(const unsigned int* __restrict__ mask, int* __restrict__ flag) {
  __shared__ int c1s;
  if (threadIdx.x == 0) c1s = 0;
  __syncthreads();
  int c1 = 0;
  for (int i = threadIdx.x; i < 16384; i += 256) {
    unsigned int u = mask[i];
    if (u & 0x0000ff00u) c1++;
  }
  atomicAdd(&c1s, c1);
  __syncthreads();
  if (threadIdx.x == 0) *flag = (c1s > 0) ? 1 : 4;  // element size in bytes
}

// ---------------------------------------------------------------------------
// Both activation converts in one launch.
__global__ void cvt_two(const float* __restrict__ a, const float* __restrict__ b,
                        unsigned short* __restrict__ oa, unsigned short* __restrict__ ob) {
  int i = blockIdx.x * 256 + threadIdx.x;
  const float* src;
  unsigned short* dst;
  int j;
  if (i < 2097152) { src = a; dst = oa; j = i; }
  else             { src = b; dst = ob; j = i - 2097152; }
  float4 v = ((const float4*)src)[j];
  ushort4 o;
  o.x = f2bf(v.x); o.y = f2bf(v.y); o.z = f2bf(v.z); o.w = f2bf(v.w);
  ((ushort4*)dst)[j] = o;
}

// All 3 weight transposes in one launch: Wt[n*512+k] = W[k*512+n]
__global__ void cvt_w3(const float* __restrict__ wq, const float* __restrict__ wk,
                       const float* __restrict__ wv,
                       unsigned short* __restrict__ oq, unsigned short* __restrict__ ok,
                       unsigned short* __restrict__ ov) {
  int idx = blockIdx.x * 256 + threadIdx.x;  // 0..786431
  int w = idx >> 18;
  int rem = idx & 262143;
  int n = rem >> 9, k = rem & 511;
  const float* W = (w == 0) ? wq : (w == 1) ? wk : wv;
  unsigned short* O = (w == 0) ? oq : (w == 1) ? ok : ov;
  O[n * 512 + k] = f2bf(W[k * 512 + n]);
}

// ---------------------------------------------------------------------------
// 256x256 tile, BK=64, 8-wave (4M x 2N), counted-vmcnt double-buffered GEMM.
// C = A[M,K] * Bt[N,K]^T, bf16 out. LDS 128 KiB dynamic.
// Swizzle: 16B-chunk ^= (row&7) on LDS (pre-swizzled global source, linear
// global_load_lds dest, swizzled ds_read) -> 2-way max bank aliasing (free).
// Sync per K-tile: barrier; stage next tile (8 loads); vmcnt(8); barrier.
// Race-free: each buffer is only staged while no wave can read it (B1 proves
// all waves finished the previous tile's ds_reads of the target buffer).
__device__ __forceinline__ void gemm256_core(
    const unsigned short* __restrict__ Ab,
    const unsigned short* __restrict__ Bb,
    unsigned short* __restrict__ C,
    long ldA, long ldB, long ldO, int nk, long bm, long bn, char* smem)
{
  const int tid = threadIdx.x;
  const int lane = tid & 63;
  const int wid = tid >> 6;
  const int wr = wid >> 1;          // 0..3: wave's 64-row M quarter
  const int wc = wid & 1;           // 0..1: wave's 128-col N half
  const int fr = lane & 15, fq = lane >> 4;

  const int srow = tid >> 3;                 // 0..63 staging row within 64-row group
  const int clog = (tid & 7) ^ (srow & 7);   // pre-swizzled source chunk (involution)

  char* buf0 = smem;
  char* buf1 = smem + 65536;

  f32x4 acc[4][8] = {};

  const int swz0 = ((fq)     ^ (fr & 7)) * 16;   // kh=0 swizzled chunk byte
  const int swz1 = ((4 + fq) ^ (fr & 7)) * 16;   // kh=1
  const int arow = (wr * 64 + fr) * 128;         // A-frag byte base (mi=0)
  const int brow = (wc * 128 + fr) * 128;        // B-frag byte base (ni=0)

  // Prologue: stage tile 0 into buf0
  {
    const unsigned short* ga = Ab + (bm + srow) * ldA + clog * 8;
    const unsigned short* gb = Bb + (bn + srow) * ldB + clog * 8;
#pragma unroll
    for (int l = 0; l < 4; ++l) {
      GLD16(ga + (long)l * 64 * ldA, buf0 + l * 8192 + tid * 16);
      GLD16(gb + (long)l * 64 * ldB, buf0 + 32768 + l * 8192 + tid * 16);
    }
  }

  char* cur = buf0;
  char* nxt = buf1;
  for (int t = 0; t < nk; ++t) {
    __builtin_amdgcn_sched_barrier(0);
    __builtin_amdgcn_s_barrier();            // B1: prev tile's reads of nxt done
    if (t + 1 < nk) {
      const long k0 = (long)(t + 1) * 64;
      const unsigned short* ga = Ab + (bm + srow) * ldA + k0 + clog * 8;
      const unsigned short* gb = Bb + (bn + srow) * ldB + k0 + clog * 8;
#pragma unroll
      for (int l = 0; l < 4; ++l) {
        GLD16(ga + (long)l * 64 * ldA, nxt + l * 8192 + tid * 16);
        GLD16(gb + (long)l * 64 * ldB, nxt + 32768 + l * 8192 + tid * 16);
      }
      asm volatile("s_waitcnt vmcnt(8)" ::: "memory");  // drain tile t's 8, keep 8 in flight
    } else {
      asm volatile("s_waitcnt vmcnt(0)" ::: "memory");
    }
    __builtin_amdgcn_s_barrier();            // B2: tile t LDS complete for all waves
    __builtin_amdgcn_sched_barrier(0);

    const char* bufA = cur;
    const char* bufB = cur + 32768;
#pragma unroll
    for (int kh = 0; kh < 2; ++kh) {
      const int swz = kh ? swz1 : swz0;
      bf16x8 a[4];
#pragma unroll
      for (int mi = 0; mi < 4; ++mi)
        a[mi] = *(const bf16x8*)(bufA + arow + mi * 2048 + swz);
#pragma unroll
      for (int nh = 0; nh < 2; ++nh) {
        bf16x8 b[4];
#pragma unroll
        for (int nj = 0; nj < 4; ++nj)
          b[nj] = *(const bf16x8*)(bufB + brow + (nh * 4 + nj) * 2048 + swz);
        __builtin_amdgcn_s_setprio(1);
#pragma unroll
        for (int mi = 0; mi < 4; ++mi)
#pragma unroll
          for (int nj = 0; nj < 4; ++nj)
            acc[mi][nh * 4 + nj] = __builtin_amdgcn_mfma_f32_16x16x32_bf16(
                a[mi], b[nj], acc[mi][nh * 4 + nj], 0, 0, 0);
        __builtin_amdgcn_s_setprio(0);
      }
    }
    char* tmp = cur; cur = nxt; nxt = tmp;
  }

  // Epilogue: C/D layout col=lane&15, row=(lane>>4)*4+r  [m89-verified]
#pragma unroll
  for (int mi = 0; mi < 4; ++mi)
#pragma unroll
    for (int ni = 0; ni < 8; ++ni) {
      const long row = bm + wr * 64 + mi * 16 + fq * 4;
      const long col = bn + wc * 128 + ni * 16 + fr;
#pragma unroll
      for (int r = 0; r < 4; ++r)
        C[(row + r) * ldO + col] = f2bf(acc[mi][ni][r]);
    }
}

// Scores: per batch S[2048x2048] = Q[2048x512] * K[2048x512]^T
__global__ __launch_bounds__(512, 2) void gemm256_scores(
    const unsigned short* __restrict__ Q, const unsigned short* __restrict__ Kb,
    unsigned short* __restrict__ S)
{
  extern __shared__ char smem[];
  const long z = blockIdx.z;
  gemm256_core(Q + z * 1048576, Kb + z * 1048576, S + z * 4194304,
               512, 512, 2048, 8, (long)blockIdx.x * 256, (long)blockIdx.y * 256, smem);
}

// Projections, one launch, grid(64,2,3):
//  z=0: Q  = Xq*Wqt^T [16384x512];  z=1: K = Xn*Wkt^T;  z=2: Vt = Wvt*Xn^T [512x16384]
__global__ __launch_bounds__(512, 2) void gemm256_proj(
    const unsigned short* __restrict__ Xq, const unsigned short* __restrict__ Xn,
    const unsigned short* __restrict__ Wqt, const unsigned short* __restrict__ Wkt,
    const unsigned short* __restrict__ Wvt,
    unsigned short* __restrict__ Q, unsigned short* __restrict__ Kb,
    unsigned short* __restrict__ Vt)
{
  extern __shared__ char smem[];
  const int z = blockIdx.z;
  if (z == 0)
    gemm256_core(Xq, Wqt, Q, 512, 512, 512, 8,
                 (long)blockIdx.x * 256, (long)blockIdx.y * 256, smem);
  else if (z == 1)
    gemm256_core(Xn, Wkt, Kb, 512, 512, 512, 8,
                 (long)blockIdx.x * 256, (long)blockIdx.y * 256, smem);
  else
    gemm256_core(Wvt, Xn, Vt, 512, 512, 16384, 8,
                 (long)blockIdx.y * 256, (long)blockIdx.x * 256, smem);
}

// ---------------------------------------------------------------------------
// m97-style 128x128 GEMM core (kept for PV: K=2048, N=512 -> 512 blocks)
__device__ __forceinline__ void gemm_core(
    const unsigned short* Ab, const unsigned short* Bb, void* Cb,
    int K, long ldB, int out_mode, long ldO, long bm, long bn,
    unsigned short (*Al)[32], unsigned short (*Bl)[32])
{
  const int t = threadIdx.x;
  const int lane = t & 63;
  const int w = t >> 6;
  const int wm = (w >> 1) * 64, wn = (w & 1) * 64;
  const int fr = lane & 15, fq = lane >> 4;

  f32x4 acc[4][4] = {};

  const int slot0 = t, slot1 = 256 + t;
  const int r0 = slot0 >> 2, s0 = slot0 & 3;
  const int r1 = slot1 >> 2, s1 = slot1 & 3;

  const int nk = K >> 5;
  for (int kt = 0; kt < nk; ++kt) {
    const long k0 = (long)kt << 5;
    GLD16(Ab + (bm + r0) * K + k0 + s0 * 8, &Al[0][0] + slot0 * 8);
    GLD16(Ab + (bm + r1) * K + k0 + s1 * 8, &Al[0][0] + slot1 * 8);
    GLD16(Bb + (bn + r0) * ldB + k0 + s0 * 8, &Bl[0][0] + slot0 * 8);
    GLD16(Bb + (bn + r1) * ldB + k0 + s1 * 8, &Bl[0][0] + slot1 * 8);
    __syncthreads();

    bf16x8 af[4], bfr[4];
#pragma unroll
    for (int mi = 0; mi < 4; ++mi)
      af[mi] = *(const bf16x8*)&Al[wm + mi * 16 + fr][fq * 8];
#pragma unroll
    for (int ni = 0; ni < 4; ++ni)
      bfr[ni] = *(const bf16x8*)&Bl[wn + ni * 16 + fr][fq * 8];
#pragma unroll
    for (int mi = 0; mi < 4; ++mi)
#pragma unroll
      for (int ni = 0; ni < 4; ++ni)
        acc[mi][ni] = __builtin_amdgcn_mfma_f32_16x16x32_bf16(af[mi], bfr[ni], acc[mi][ni], 0, 0, 0);
    __syncthreads();
  }

  if (out_mode == 2) {
    float* C = (float*)Cb;
#pragma unroll
    for (int mi = 0; mi < 4; ++mi)
#pragma unroll
      for (int ni = 0; ni < 4; ++ni) {
        const long row = bm + wm + mi * 16 + fq * 4;
        const long col = bn + wn + ni * 16 + fr;
#pragma unroll
        for (int r = 0; r < 4; ++r)
          C[(row + r) * ldO + col] = acc[mi][ni][r];
      }
  } else {
    unsigned short* C = (unsigned short*)Cb;
#pragma unroll
    for (int mi = 0; mi < 4; ++mi)
#pragma unroll
      for (int ni = 0; ni < 4; ++ni) {
        const long row = bm + wm + mi * 16 + fq * 4;
        const long col = bn + wn + ni * 16 + fr;
#pragma unroll
        for (int r = 0; r < 4; ++r)
          C[(row + r) * ldO + col] = f2bf(acc[mi][ni][r]);
      }
  }
}

__global__ __launch_bounds__(256) void gemm_bt(
    const unsigned short* __restrict__ A,
    const unsigned short* __restrict__ Bt,
    void* __restrict__ Cout,
    int K, long ldB,
    long batchA, long batchB, long batchC,
    int out_mode, long ldO, int out_f32)
{
  __shared__ unsigned short Al[128][32];
  __shared__ unsigned short Bl[128][32];
  const unsigned short* Ab = A + (size_t)blockIdx.z * batchA;
  const unsigned short* Bb = Bt + (size_t)blockIdx.z * batchB;
  char* Cb = (char*)Cout + (size_t)blockIdx.z * batchC * (out_f32 ? 4 : 2);
  gemm_core(Ab, Bb, Cb, K, ldB, out_mode, ldO,
            (long)blockIdx.x * 128, (long)blockIdx.y * 128, Al, Bl);
}

// ---------------------------------------------------------------------------
// Masked scaled softmax over rows of S (bf16, in place). Mask flat-elementwise.
__global__ __launch_bounds__(256) void softmax_rows(
    unsigned short* __restrict__ S,
    const unsigned char* __restrict__ mask,
    const int* __restrict__ flag)
{
  const int t = threadIdx.x;
  const size_t base = (size_t)blockIdx.x * 2048 + (size_t)t * 8;
  uint4 sv = *(const uint4*)(S + base);

  float x[8];
  {
    unsigned int w0 = sv.x, w1 = sv.y, w2 = sv.z, w3 = sv.w;
    x[0] = bf2f((unsigned short)(w0 & 0xffff)); x[1] = bf2f((unsigned short)(w0 >> 16));
    x[2] = bf2f((unsigned short)(w1 & 0xffff)); x[3] = bf2f((unsigned short)(w1 >> 16));
    x[4] = bf2f((unsigned short)(w2 & 0xffff)); x[5] = bf2f((unsigned short)(w2 >> 16));
    x[6] = bf2f((unsigned short)(w3 & 0xffff)); x[7] = bf2f((unsigned short)(w3 >> 16));
  }

  const int esz = *flag;
  unsigned int mbits = 0;
  if (esz == 1) {
    unsigned long long mv = *(const unsigned long long*)(mask + base);
#pragma unroll
    for (int j = 0; j < 8; ++j)
      if ((mv >> (8 * j)) & 0xffULL) mbits |= 1u << j;
  } else {
    const uint4* mp = (const uint4*)(mask + base * 4);
    uint4 a = mp[0], b = mp[1];
    if (a.x) mbits |= 1u;   if (a.y) mbits |= 2u;
    if (a.z) mbits |= 4u;   if (a.w) mbits |= 8u;
    if (b.x) mbits |= 16u;  if (b.y) mbits |= 32u;
    if (b.z) mbits |= 64u;  if (b.w) mbits |= 128u;
  }

  const float SCALE = 0.04419417382415922f;  // 1/sqrt(512)
  float xs[8];
#pragma unroll
  for (int j = 0; j < 8; ++j) {
    float v = ((mbits >> j) & 1u) ? -3.4028234663852886e38f : x[j];
    xs[j] = v * SCALE;
  }

  float m = xs[0];
#pragma unroll
  for (int j = 1; j < 8; ++j) m = fmaxf(m, xs[j]);
#pragma unroll
  for (int off = 32; off > 0; off >>= 1) m = fmaxf(m, __shfl_xor(m, off));

  __shared__ float rm[4], rs[4];
  if ((t & 63) == 0) rm[t >> 6] = m;
  __syncthreads();
  m = fmaxf(fmaxf(rm[0], rm[1]), fmaxf(rm[2], rm[3]));

  float e[8], ssum = 0.f;
#pragma unroll
  for (int j = 0; j < 8; ++j) { e[j] = __expf(xs[j] - m); ssum += e[j]; }
#pragma unroll
  for (int off = 32; off > 0; off >>= 1) ssum += __shfl_xor(ssum, off);
  if ((t & 63) == 0) rs[t >> 6] = ssum;
  __syncthreads();
  ssum = rs[0] + rs[1] + rs[2] + rs[3];
  const float inv = 1.0f / ssum;

  unsigned int o0 = (unsigned int)f2bf(e[0] * inv) | ((unsigned int)f2bf(e[1] * inv) << 16);
  unsigned int o1 = (unsigned int)f2bf(e[2] * inv) | ((unsigned int)f2bf(e[3] * inv) << 16);
  unsigned int o2 = (unsigned int)f2bf(e[4] * inv) | ((unsigned int)f2bf(e[5] * inv) << 16);
  unsigned int o3 = (unsigned int)f2bf(e[6] * inv) | ((unsigned int)f2bf(e[7] * inv) << 16);
  uint4 ov; ov.x = o0; ov.y = o1; ov.z = o2; ov.w = o3;
  *(uint4*)(S + base) = ov;
}

// ---------------------------------------------------------------------------
extern "C" void kernel_launch(void* const* d_in, const int* in_sizes, int n_in,
                              void* d_out, int out_size, void* d_ws, size_t ws_size,
                              hipStream_t stream) {
  const float* node  = (const float*)d_in[0];
  const float* query = (const float*)d_in[1];
  const unsigned char* mask = (const unsigned char*)d_in[2];
  const float* wq = (const float*)d_in[3];
  const float* wk = (const float*)d_in[4];
  const float* wv = (const float*)d_in[5];
  float* out = (float*)d_out;

  char* ws = (char*)d_ws;
  unsigned short* Q   = (unsigned short*)(ws);
  unsigned short* Kb  = (unsigned short*)(ws + 16777216);
  unsigned short* Vt  = (unsigned short*)(ws + 33554432);
  unsigned short* S   = (unsigned short*)(ws + 50331648);
  unsigned short* Xq  = (unsigned short*)(ws + 50331648);
  unsigned short* Xn  = (unsigned short*)(ws + 50331648 + 16777216);
  unsigned short* Wqt = (unsigned short*)(ws + 50331648 + 33554432);
  unsigned short* Wkt = Wqt + 262144;
  unsigned short* Wvt = Wkt + 262144;
  int* flag = (int*)(ws + 117440512);

  detect_mode<<<1, 256, 0, stream>>>((const unsigned int*)mask, flag);

  cvt_two<<<16384, 256, 0, stream>>>(query, node, Xq, Xn);
  cvt_w3<<<3072, 256, 0, stream>>>(wq, wk, wv, Wqt, Wkt, Wvt);

  // Projections (one launch, 256^2 counted-vmcnt kernel): Q, K, Vt
  dim3 gp(64, 2, 3);
  gemm256_proj<<<gp, 512, 131072, stream>>>(Xq, Xn, Wqt, Wkt, Wvt, Q, Kb, Vt);

  // Scores: per batch [2048x512] * [2048x512]^T -> S bf16 [2048x2048]
  dim3 gs(8, 8, 8);
  gemm256_scores<<<gs, 512, 131072, stream>>>(Q, Kb, S);

  // Masked scaled softmax over each row of S (in place)
  softmax_rows<<<16384, 256, 0, stream>>>(S, mask, flag);

  // PV: per batch [2048x2048] * Vt[512x16384 (+b*2048)]^T -> out f32 [2048x512]
  dim3 gv(16, 4, 8);
  gemm_bt<<<gv, 256, 0, stream>>>(S, Vt, out, 2048, 16384,
                                  4194304L, 2048L, 1048576L, 2, 512, 1);
}